// Round 10
// baseline (525.392 us; speedup 1.0000x reference)
//
#include <hip/hip_runtime.h>
#include <math.h>

// Problem constants
#define Bn 256
#define Ln 256
#define Dn 128
#define Hn 2
#define En 64
#define NLn 2
#define TOPKn 5
#define NUM_TOTALn 100000
#define BLD (Bn*Ln*Dn)      // 8388608 elements per activation buffer (bf16)
#define WT_LAYER 147456     // bf16 elements of weights per layer (incl W2T)

using frag_ab = __attribute__((ext_vector_type(8))) short;   // 8 bf16
using frag_cd = __attribute__((ext_vector_type(4))) float;   // 4 f32

__device__ inline short f2bf(float f) {
    union { float f; unsigned u; } c; c.f = f;
    unsigned r = (c.u + 0x7FFFu + ((c.u >> 16) & 1u)) >> 16;   // RNE
    return (short)r;
}
__device__ inline float bf2f(short s) {
    union { unsigned u; float f; } c; c.u = ((unsigned)(unsigned short)s) << 16;
    return c.f;
}

// ---------------------------------------------------------------------------
__global__ void beacon_kernel(float* out, float v) { out[0] = v; }

// Band-pass impulse response g_k[delta]; k=0: f in [51,128] (incl Nyquist),
// k=1: f in [0,77] (incl DC).
__global__ __launch_bounds__(256) void build_g_kernel(float* __restrict__ g) {
    int k = blockIdx.x;
    int d = threadIdx.x;
    int f1 = (k == 0) ? 51 : 1;
    int f2 = (k == 0) ? 127 : 77;
    double acc = (k == 0) ? 0.0 : 1.0;
    const double twopi_over_L = 6.283185307179586476925286766559 / 256.0;
    for (int f = f1; f <= f2; f++) acc += 2.0 * cos(twopi_over_L * (double)f * (double)d);
    if (k == 0) acc += (d & 1) ? -1.0 : 1.0;
    g[k * 256 + d] = (float)(acc / 256.0);
}

// Circulant matrices G_k[t][s] = g_k[(t-s)&255], stored bf16 (GEMM A operand)
__global__ __launch_bounds__(256) void build_G_kernel(const float* __restrict__ g,
                                                      short* __restrict__ G) {
    int k = blockIdx.x, t = blockIdx.y, s = threadIdx.x;
    G[((size_t)k * 256 + t) * 256 + s] = f2bf(g[k * 256 + ((t - s) & 255)]);
}

// x[b,t,d] = ego[paths[b,t], d] + pos[t, d]  -> bf16
__global__ __launch_bounds__(256) void build_x_kernel(const int* __restrict__ paths,
                                                      const float* __restrict__ ego,
                                                      const float* __restrict__ pos,
                                                      short* __restrict__ x) {
    int base = (blockIdx.x * 256 + threadIdx.x) * 4;
    int d = base & 127;
    int bl = base >> 7;
    int t = bl & 255;
    float4 e = *(const float4*)(ego + (size_t)paths[bl] * Dn + d);
    float4 p = *(const float4*)(pos + t * Dn + d);
    short4 s;
    s.x = f2bf(e.x + p.x); s.y = f2bf(e.y + p.y);
    s.z = f2bf(e.z + p.z); s.w = f2bf(e.w + p.w);
    *(short4*)&x[base] = s;
}

__global__ __launch_bounds__(256) void zero_mv_kernel(float* __restrict__ mv) {
    mv[blockIdx.x * 256 + threadIdx.x] = 0.0f;
}

// Weight cast+transpose+scale: in f32 [z][K][N] -> out bf16 [z][N][K] * scale
__global__ __launch_bounds__(256) void wtrans_kernel(const float* __restrict__ in,
                                                     short* __restrict__ out,
                                                     int K, int nmask, int nshift,
                                                     long long outLayerStride,
                                                     float scale) {
    int z = blockIdx.y;
    int idx = blockIdx.x * 256 + threadIdx.x;
    int n = idx & nmask;
    int k = idx >> nshift;
    out[(size_t)z * outLayerStride + (size_t)n * K + k] =
        f2bf(scale * in[(size_t)z * ((size_t)(nmask + 1) * K) + idx]);
}

// ---------------------------------------------------------------------------
// General MFMA bf16 GEMM (used for the circulant filter + W2T precompute).
// A bf16 [M][K].  BT_FAST: B bf16 [N][K]; else B bf16 [K][N] transpose-staged.
// Operand-swapped MFMA -> coalesced short4 epilogue; register prefetch.
template<bool BT_FAST, bool GELU_EPI>
__global__ __launch_bounds__(256)
void mfma_gemm_kernel(const short* A, const short* Bp, short* C, const short* R,
                      int K, int lda, int ldb, int ldc, int ldr,
                      long long sA, long long sB, long long sC, long long sR,
                      long long sCsplit, float alpha, float beta) {
    int bz = blockIdx.z;
    A += (size_t)bz * sA; C += (size_t)bz * sC;
    if (R) R += (size_t)bz * sR;
    const short* Bt = Bp + (size_t)bz * sB;
    const int m0 = blockIdx.x * 128, n0 = blockIdx.y * 128;
    int n0c = n0;
    if (sCsplit) { C += (size_t)blockIdx.y * sCsplit; n0c = 0; }
    __shared__ short As[128 * 40];
    __shared__ short Bs[128 * 40];
    int tid = threadIdx.x;
    int lane = tid & 63, wave = tid >> 6;
    int wr = (wave >> 1) * 64, wc = (wave & 1) * 64;
    int l15 = lane & 15, qd = lane >> 4;

    frag_cd zero4 = {0.f, 0.f, 0.f, 0.f};
    frag_cd acc[4][4];
    #pragma unroll
    for (int i = 0; i < 4; i++)
        #pragma unroll
        for (int j = 0; j < 4; j++) acc[i][j] = zero4;

    int arow = tid >> 1, acg = (tid & 1) * 16;
    int bnrow = tid >> 1, bcg = (tid & 1) * 16;
    int bkk = tid & 31, bnb = (tid >> 5) * 16;

    int4 pa0, pa1, pb0, pb1;
    {
        const short* ap = A + (size_t)(m0 + arow) * lda + acg;
        pa0 = *(const int4*)ap; pa1 = *(const int4*)(ap + 8);
        if (BT_FAST) {
            const short* bp = Bt + (size_t)(n0 + bnrow) * ldb + bcg;
            pb0 = *(const int4*)bp; pb1 = *(const int4*)(bp + 8);
        } else {
            const short* bp = Bt + (size_t)bkk * ldb + n0 + bnb;
            pb0 = *(const int4*)bp; pb1 = *(const int4*)(bp + 8);
        }
    }

    for (int k0 = 0; k0 < K; k0 += 32) {
        __syncthreads();
        *(int4*)&As[arow * 40 + acg] = pa0;
        *(int4*)&As[arow * 40 + acg + 8] = pa1;
        if (BT_FAST) {
            *(int4*)&Bs[bnrow * 40 + bcg] = pb0;
            *(int4*)&Bs[bnrow * 40 + bcg + 8] = pb1;
        } else {
            short tmp[16];
            *(int4*)&tmp[0] = pb0; *(int4*)&tmp[8] = pb1;
            #pragma unroll
            for (int i = 0; i < 16; i++) Bs[(bnb + i) * 40 + bkk] = tmp[i];
        }
        __syncthreads();
        if (k0 + 32 < K) {
            const short* ap = A + (size_t)(m0 + arow) * lda + k0 + 32 + acg;
            pa0 = *(const int4*)ap; pa1 = *(const int4*)(ap + 8);
            if (BT_FAST) {
                const short* bp = Bt + (size_t)(n0 + bnrow) * ldb + k0 + 32 + bcg;
                pb0 = *(const int4*)bp; pb1 = *(const int4*)(bp + 8);
            } else {
                const short* bp = Bt + (size_t)(k0 + 32 + bkk) * ldb + n0 + bnb;
                pb0 = *(const int4*)bp; pb1 = *(const int4*)(bp + 8);
            }
        }
        frag_ab af[4], bf[4];
        #pragma unroll
        for (int ms = 0; ms < 4; ms++)
            af[ms] = *(frag_ab*)&As[(wr + ms * 16 + l15) * 40 + qd * 8];
        #pragma unroll
        for (int ns = 0; ns < 4; ns++)
            bf[ns] = *(frag_ab*)&Bs[(wc + ns * 16 + l15) * 40 + qd * 8];
        #pragma unroll
        for (int ms = 0; ms < 4; ms++)
            #pragma unroll
            for (int ns = 0; ns < 4; ns++)
                acc[ms][ns] = __builtin_amdgcn_mfma_f32_16x16x32_bf16(
                    bf[ns], af[ms], acc[ms][ns], 0, 0, 0);
    }
    #pragma unroll
    for (int ms = 0; ms < 4; ms++) {
        int m = m0 + wr + ms * 16 + l15;
        #pragma unroll
        for (int ns = 0; ns < 4; ns++) {
            int nb = wc + ns * 16 + qd * 4;
            float v[4];
            #pragma unroll
            for (int r = 0; r < 4; r++) v[r] = alpha * acc[ms][ns][r];
            if (R) {
                short4 r4 = *(const short4*)&R[(size_t)m * ldr + n0 + nb];
                v[0] += beta * bf2f(r4.x); v[1] += beta * bf2f(r4.y);
                v[2] += beta * bf2f(r4.z); v[3] += beta * bf2f(r4.w);
            }
            if (GELU_EPI) {
                #pragma unroll
                for (int r = 0; r < 4; r++)
                    v[r] = v[r] * 0.5f * (1.0f + erff(v[r] * 0.70710678118654752f));
            }
            short4 o;
            o.x = f2bf(v[0]); o.y = f2bf(v[1]); o.z = f2bf(v[2]); o.w = f2bf(v[3]);
            *(short4*)&C[(size_t)m * ldc + n0c + nb] = o;
        }
    }
}

static inline void mgemm(hipStream_t s, const short* A, const short* B, short* C,
                         const short* R, int M, int N, int K,
                         int lda, int ldb, int ldc, int ldr,
                         long long sA, long long sB, long long sC, long long sR,
                         int batch, float alpha, float beta, bool btFast, bool gelu,
                         long long sCsplit = 0) {
    dim3 grid(M / 128, N / 128, batch), block(256);
    if (btFast) {
        if (gelu) mfma_gemm_kernel<true, true ><<<grid, block, 0, s>>>(A, B, C, R, K, lda, ldb, ldc, ldr, sA, sB, sC, sR, sCsplit, alpha, beta);
        else      mfma_gemm_kernel<true, false><<<grid, block, 0, s>>>(A, B, C, R, K, lda, ldb, ldc, ldr, sA, sB, sC, sR, sCsplit, alpha, beta);
    } else {
        if (gelu) mfma_gemm_kernel<false, true ><<<grid, block, 0, s>>>(A, B, C, R, K, lda, ldb, ldc, ldr, sA, sB, sC, sR, sCsplit, alpha, beta);
        else      mfma_gemm_kernel<false, false><<<grid, block, 0, s>>>(A, B, C, R, K, lda, ldb, ldc, ldr, sA, sB, sC, sR, sCsplit, alpha, beta);
    }
}

// ---------------------------------------------------------------------------
// B-resident thin-K weight GEMM:  C = A1@B1 [+ A2@B2] + R  (+opt GELU).
// B (pre-transposed bf16 [N][K]) staged to LDS ONCE per 128-K chunk; the
// K-loop then runs with ZERO barriers: A-fragments loaded directly
// global->VGPR (16B/lane, 64B-contiguous per quad).  A row stride == K.
// 256 thr = 4 waves, 64x64/wave.  grid.y = N/128 (B offset n0*K).
// sCsplit: split-C fused multi-output.  beta = 1 when R given.
template<bool DUAL, bool GELU_EPI>
__global__ __launch_bounds__(256, 4)
void wgemm_kernel(const short* __restrict__ A1, const short* __restrict__ B1, int K1,
                  const short* __restrict__ A2, const short* __restrict__ B2, int K2,
                  short* C, const short* __restrict__ R, int ldc, int ldr,
                  long long sCsplit) {
    const int m0 = blockIdx.x * 128;
    const int n0 = blockIdx.y * 128;
    int n0c = n0;
    if (sCsplit) { C += (size_t)blockIdx.y * sCsplit; n0c = 0; }
    __shared__ short Bs[128 * 132];   // one 128n x 128k chunk, stride 132
    int tid = threadIdx.x;
    int lane = tid & 63, wave = tid >> 6;
    int wr = (wave >> 1) * 64, wc = (wave & 1) * 64;
    int l15 = lane & 15, qd = lane >> 4;

    frag_cd zero4 = {0.f, 0.f, 0.f, 0.f};
    frag_cd acc[4][4];
    #pragma unroll
    for (int i = 0; i < 4; i++)
        #pragma unroll
        for (int j = 0; j < 4; j++) acc[i][j] = zero4;

    int nst = tid >> 1, kst = (tid & 1) * 64;

    #pragma unroll
    for (int pass = 0; pass < (DUAL ? 2 : 1); pass++) {
        const short* A = pass ? A2 : A1;
        const short* B = pass ? B2 : B1;
        int K = pass ? K2 : K1;
        const short* Bn0 = B + (size_t)n0 * K;
        for (int kb0 = 0; kb0 < K; kb0 += 128) {
            __syncthreads();   // protect Bs from previous chunk's readers
            {
                const short* bp = Bn0 + (size_t)nst * K + kb0 + kst;
                #pragma unroll
                for (int i = 0; i < 8; i++)
                    *(int4*)&Bs[nst * 132 + kst + i * 8] = *(const int4*)(bp + i * 8);
            }
            __syncthreads();
            const short* Ab = A + (size_t)(m0 + wr + l15) * K + kb0 + qd * 8;
            #pragma unroll
            for (int k0 = 0; k0 < 128; k0 += 32) {
                frag_ab af[4], bf[4];
                #pragma unroll
                for (int ms = 0; ms < 4; ms++)
                    af[ms] = *(const frag_ab*)(Ab + (size_t)ms * 16 * K + k0);
                #pragma unroll
                for (int ns = 0; ns < 4; ns++)
                    bf[ns] = *(frag_ab*)&Bs[(wc + ns * 16 + l15) * 132 + k0 + qd * 8];
                #pragma unroll
                for (int ms = 0; ms < 4; ms++)
                    #pragma unroll
                    for (int ns = 0; ns < 4; ns++)
                        acc[ms][ns] = __builtin_amdgcn_mfma_f32_16x16x32_bf16(
                            bf[ns], af[ms], acc[ms][ns], 0, 0, 0);
            }
        }
    }
    #pragma unroll
    for (int ms = 0; ms < 4; ms++) {
        int m = m0 + wr + ms * 16 + l15;
        #pragma unroll
        for (int ns = 0; ns < 4; ns++) {
            int nb = wc + ns * 16 + qd * 4;
            float v[4];
            #pragma unroll
            for (int r = 0; r < 4; r++) v[r] = acc[ms][ns][r];
            if (R) {
                short4 r4 = *(const short4*)&R[(size_t)m * ldr + n0 + nb];
                v[0] += bf2f(r4.x); v[1] += bf2f(r4.y);
                v[2] += bf2f(r4.z); v[3] += bf2f(r4.w);
            }
            if (GELU_EPI) {
                #pragma unroll
                for (int r = 0; r < 4; r++)
                    v[r] = v[r] * 0.5f * (1.0f + erff(v[r] * 0.70710678118654752f));
            }
            short4 o;
            o.x = f2bf(v[0]); o.y = f2bf(v[1]); o.z = f2bf(v[2]); o.w = f2bf(v[3]);
            *(short4*)&C[(size_t)m * ldc + n0c + nb] = o;
        }
    }
}

// ---------------------------------------------------------------------------
// MFMA bf16 fused attention, one WG per (h, b).  512 threads = 8 waves.
// Fixed-max softmax (scores O(0.01)).  S stored DIAGONALLY (SD[tau][keyLocal],
// stride 66 -> conflict-free mv reduction).  Denominator via ones-column in vT.
__global__ __launch_bounds__(512, 4) void attn_kernel(short* q,
        const short* __restrict__ kb, const short* __restrict__ vf,
        const int* __restrict__ paths, float* __restrict__ mv) {
    int h = blockIdx.x, b = blockIdx.y;
    __shared__ short SB[256 * 72];   // phase0: q staging (stride 72); loop: SD (stride 66)
    __shared__ short ks[64 * 72];
    __shared__ short vT[80 * 72];
    __shared__ float masks[256];
    __shared__ float mvpart[512];
    int tid = threadIdx.x;
    int lane = tid & 63, wave = tid >> 6;
    int l15 = lane & 15, qd = lane >> 4;
    if (tid < 256) masks[tid] = (paths[b * 256 + tid] < NUM_TOTALn) ? 0.0f : -10000.0f;
    {
        int e0 = tid * 2;
        #pragma unroll
        for (int i = 0; i < 2; i++) {
            int e = e0 + i;
            int row = 64 + (e >> 6), col = e & 63;
            vT[row * 72 + col] = (row == 64) ? (short)0x3F80 : (short)0;
        }
    }
    short* qg = q + ((size_t)b << 15) + (size_t)h * 64;
    const short* kg = kb + ((size_t)b << 15) + (size_t)h * 64;
    const short* vg = vf + ((size_t)b << 15) + (size_t)h * 64;

    #pragma unroll
    for (int p = 0; p < 4; p++) {
        int chunk = p * 512 + tid;
        int r = chunk >> 3, cb = (chunk & 7) * 8;
        *(frag_ab*)&SB[r * 72 + cb] = *(const frag_ab*)(qg + (size_t)r * 128 + cb);
    }
    __syncthreads();
    int myrow = wave * 32;
    frag_ab aq[2][2];
    #pragma unroll
    for (int mt = 0; mt < 2; mt++)
        #pragma unroll
        for (int hf = 0; hf < 2; hf++)
            aq[mt][hf] = *(frag_ab*)&SB[(myrow + mt * 16 + l15) * 72 + hf * 32 + qd * 8];

    frag_cd zero4 = {0.f, 0.f, 0.f, 0.f};
    frag_cd oacc[2][5];
    #pragma unroll
    for (int mt = 0; mt < 2; mt++)
        #pragma unroll
        for (int et = 0; et < 5; et++) oacc[mt][et] = zero4;
    float macc = 0.0f;
    int tau = tid & 255, half = tid >> 8;

    for (int jt = 0; jt < 4; jt++) {
        __syncthreads();
        {
            int r = tid >> 3, cb = (tid & 7) * 8;
            *(frag_ab*)&ks[r * 72 + cb] =
                *(const frag_ab*)(kg + (size_t)(jt * 64 + r) * 128 + cb);
            frag_ab v8 = *(const frag_ab*)(vg + (size_t)(jt * 64 + r) * 128 + cb);
            #pragma unroll
            for (int i = 0; i < 8; i++) vT[(cb + i) * 72 + r] = v8[i];
        }
        __syncthreads();
        #pragma unroll
        for (int mt = 0; mt < 2; mt++) {
            #pragma unroll
            for (int nt = 0; nt < 4; nt++) {
                frag_ab b0 = *(frag_ab*)&ks[(nt * 16 + l15) * 72 + qd * 8];
                frag_ab b1 = *(frag_ab*)&ks[(nt * 16 + l15) * 72 + 32 + qd * 8];
                frag_cd c = zero4;
                c = __builtin_amdgcn_mfma_f32_16x16x32_bf16(aq[mt][0], b0, c, 0, 0, 0);
                c = __builtin_amdgcn_mfma_f32_16x16x32_bf16(aq[mt][1], b1, c, 0, 0, 0);
                int keyLocal = nt * 16 + l15;
                #pragma unroll
                for (int r = 0; r < 4; r++) {
                    int row = myrow + mt * 16 + qd * 4 + r;
                    int tt = (row - jt * 64 - keyLocal) & 255;
                    SB[tt * 66 + keyLocal] = f2bf(c[r] * 0.125f);
                }
            }
        }
        __syncthreads();
        {
            const int* SD32 = (const int*)&SB[tau * 66 + half * 32];
            #pragma unroll
            for (int i = 0; i < 16; i++) {
                int pk = SD32[i];
                macc += bf2f((short)(pk & 0xFFFF)) + bf2f((short)(pk >> 16));
            }
        }
        #pragma unroll
        for (int mt = 0; mt < 2; mt++) {
            int row = myrow + mt * 16 + l15;
            #pragma unroll
            for (int hf = 0; hf < 2; hf++) {
                int kl0 = hf * 32 + qd * 8;
                frag_ab pfrag;
                #pragma unroll
                for (int j = 0; j < 8; j++) {
                    int kl = kl0 + j;
                    int tt = (row - jt * 64 - kl) & 255;
                    float s = bf2f(SB[tt * 66 + kl]);
                    pfrag[j] = f2bf(__expf(s + masks[jt * 64 + kl]));
                }
                #pragma unroll
                for (int et = 0; et < 5; et++) {
                    frag_ab bv = *(frag_ab*)&vT[(et * 16 + l15) * 72 + hf * 32 + qd * 8];
                    oacc[mt][et] = __builtin_amdgcn_mfma_f32_16x16x32_bf16(pfrag, bv, oacc[mt][et], 0, 0, 0);
                }
            }
        }
    }
    __syncthreads();
    mvpart[tid] = macc;
    __syncthreads();
    if (tid < 256)
        atomicAdd(&mv[b * 256 + tid], (mvpart[tid] + mvpart[tid + 256]) * 0.0625f);
    #pragma unroll
    for (int mt = 0; mt < 2; mt++) {
        #pragma unroll
        for (int r = 0; r < 4; r++) {
            float l = oacc[mt][4][r];
            l = __shfl(l, (lane & 48));
            float inv = 1.0f / l;
            int row = myrow + mt * 16 + qd * 4 + r;
            #pragma unroll
            for (int et = 0; et < 4; et++)
                qg[(size_t)row * 128 + et * 16 + l15] = f2bf(oacc[mt][et][r] * inv);
        }
    }
}

// ---------------------------------------------------------------------------
__global__ __launch_bounds__(256) void gm_reduce_kernel(const float* __restrict__ mv,
                                                        float* __restrict__ gm) {
    int tau = blockIdx.x;
    int b = threadIdx.x;
    __shared__ float red[256];
    red[b] = mv[b * 256 + tau];
    __syncthreads();
    for (int s = 128; s > 0; s >>= 1) { if (b < s) red[b] += red[b + s]; __syncthreads(); }
    if (b == 0) gm[tau] = red[0] * (1.0f / 256.0f);
}

__global__ __launch_bounds__(256) void topk_softmax_kernel(const float* __restrict__ gm,
                                                           const float* __restrict__ mv,
                                                           int* __restrict__ delays,
                                                           float* __restrict__ tc) {
    __shared__ float vsh[256];
    __shared__ int ish[256];
    __shared__ int dsh[TOPKn];
    int tid = threadIdx.x;
    float v = gm[tid];
    for (int t = 0; t < TOPKn; t++) {
        vsh[tid] = v; ish[tid] = tid;
        __syncthreads();
        for (int s = 128; s > 0; s >>= 1) {
            if (tid < s) {
                float v2 = vsh[tid + s]; int i2 = ish[tid + s];
                if (v2 > vsh[tid] || (v2 == vsh[tid] && i2 < ish[tid])) {
                    vsh[tid] = v2; ish[tid] = i2;
                }
            }
            __syncthreads();
        }
        if (tid == 0) { dsh[t] = ish[0]; delays[t] = ish[0]; }
        __syncthreads();
        if (tid == dsh[t]) v = -1e30f;
        __syncthreads();
    }
    int b = tid;
    float w[TOPKn];
    float m = -1e30f;
    #pragma unroll
    for (int j = 0; j < TOPKn; j++) { w[j] = mv[b * 256 + dsh[j]]; m = fmaxf(m, w[j]); }
    float ssum = 0.0f;
    #pragma unroll
    for (int j = 0; j < TOPKn; j++) { w[j] = expf(w[j] - m); ssum += w[j]; }
    #pragma unroll
    for (int j = 0; j < TOPKn; j++) tc[b * TOPKn + j] = w[j] / ssum;
}

__global__ __launch_bounds__(256) void mix_kernel(const short* __restrict__ x,
                                                  const float* __restrict__ tc,
                                                  const int* __restrict__ delays,
                                                  short* __restrict__ out) {
    int idx = (blockIdx.x * 256 + threadIdx.x) * 8;
    int d = idx & 127;
    int t = (idx >> 7) & 255;
    int b = idx >> 15;
    const short* xb = x + ((size_t)b << 15);
    float acc[8] = {0, 0, 0, 0, 0, 0, 0, 0};
    #pragma unroll
    for (int j = 0; j < TOPKn; j++) {
        float w = tc[b * TOPKn + j];
        frag_ab v8 = *(const frag_ab*)(xb + (((t + delays[j]) & 255) << 7) + d);
        #pragma unroll
        for (int i = 0; i < 8; i++) acc[i] += w * bf2f(v8[i]);
    }
    frag_ab o;
    #pragma unroll
    for (int i = 0; i < 8; i++) o[i] = f2bf(acc[i]);
    *(frag_ab*)(out + idx) = o;
}

__global__ __launch_bounds__(256) void gather_out_kernel(const short* __restrict__ x,
                                                         const int* __restrict__ lengths,
                                                         float* __restrict__ out) {
    int idx = blockIdx.x * 256 + threadIdx.x;
    int d = idx & 127;
    int b = idx >> 7;
    out[idx] = bf2f(x[((size_t)b << 15) + (size_t)(lengths[b] - 1) * Dn + d]);
}

// ---------------------------------------------------------------------------
extern "C" void kernel_launch(void* const* d_in, const int* in_sizes, int n_in,
                              void* d_out, int out_size, void* d_ws, size_t ws_size,
                              hipStream_t stream) {
    const int* paths    = (const int*)d_in[0];
    const int* lengths  = (const int*)d_in[1];
    const float* ego    = (const float*)d_in[4];
    const float* pos    = (const float*)d_in[5];
    const float* Wq     = (const float*)d_in[6];
    const float* Wk     = (const float*)d_in[7];
    const float* Wv     = (const float*)d_in[8];
    const float* Wp     = (const float*)d_in[9];
    const float* F1     = (const float*)d_in[10];
    const float* F2     = (const float*)d_in[11];
    float* out = (float*)d_out;

    const size_t need = (size_t)5 * BLD * 2 + 512 * 4 + 131072 * 2 + 65536 * 4
                        + 256 * 4 + 1280 * 4 + 16 * 4 + (size_t)NLn * WT_LAYER * 2;
    if (ws_size < need) {
        beacon_kernel<<<dim3(1), dim3(1), 0, stream>>>(out, (float)(ws_size >> 20));
        return;
    }

    short* x    = (short*)d_ws;
    short* q    = x + (size_t)1 * BLD;   // q~ -> spat
    short* kb   = x + (size_t)2 * BLD;   // k~ -> a
    short* vf   = x + (size_t)3 * BLD;   // v~ -> h (spans vf+x5)
    short* x5   = x + (size_t)4 * BLD;   // xf -> tmpmix -> h(hi)
    float* g    = (float*)(x + (size_t)5 * BLD);
    short* Gb   = (short*)(g + 512);
    float* mv   = (float*)(Gb + 131072);
    float* gm   = mv + 65536;
    float* tc   = gm + 256;
    int* delays = (int*)(tc + 1280);
    short* Wt   = (short*)(delays + 16);

    build_g_kernel<<<dim3(2), dim3(256), 0, stream>>>(g);
    build_G_kernel<<<dim3(2, 256), dim3(256), 0, stream>>>(g, Gb);
    build_x_kernel<<<dim3(BLD / 1024), dim3(256), 0, stream>>>(paths, ego, pos, x);

    // Wt per layer: [0]=Wq^T | [16384]=Wk^T | [32768]=Wv^T | [49152]=0.1*Wp^T
    //               [65536]=F1^T | [98304]=F2^T | [131072]=W2^T=0.9*(Wv@Wp)^T
    wtrans_kernel<<<dim3(64, NLn),  dim3(256), 0, stream>>>(Wq, Wt + 0,     128, 127, 7, WT_LAYER, 1.0f);
    wtrans_kernel<<<dim3(64, NLn),  dim3(256), 0, stream>>>(Wk, Wt + 16384, 128, 127, 7, WT_LAYER, 1.0f);
    wtrans_kernel<<<dim3(64, NLn),  dim3(256), 0, stream>>>(Wv, Wt + 32768, 128, 127, 7, WT_LAYER, 1.0f);
    wtrans_kernel<<<dim3(64, NLn),  dim3(256), 0, stream>>>(Wp, Wt + 49152, 128, 127, 7, WT_LAYER, 0.1f);
    wtrans_kernel<<<dim3(128, NLn), dim3(256), 0, stream>>>(F1, Wt + 65536, 128, 255, 8, WT_LAYER, 1.0f);
    wtrans_kernel<<<dim3(128, NLn), dim3(256), 0, stream>>>(F2, Wt + 98304, 256, 127, 7, WT_LAYER, 1.0f);
    for (int k = 0; k < NLn; k++) {
        short* WtL = Wt + (size_t)k * WT_LAYER;
        mgemm(stream, WtL + 49152, WtL + 32768, WtL + 131072, nullptr,
              128, 128, 128, 128, 128, 128, 0, 0, 0, 0, 0, 1,
              9.0f, 0.0f, false, false);
    }

    for (int k = 0; k < NLn; k++) {
        const short* WtL = Wt + (size_t)k * WT_LAYER;
        // xf = G_k @ x[b] (band filter; slow-path B) -> x5
        mgemm(stream, Gb + (size_t)k * 65536, x, x5, nullptr,
              256, 128, 256, 256, 128, 128, 0,
              0, 32768, 32768, 0, 256, 1.0f, 0.0f, false, false);
        // fused projections: A=x5, B=[Wq^T;Wk^T;Wv^T], N=384 split-C
        wgemm_kernel<false, false><<<dim3(512, 3), dim3(256), 0, stream>>>(
            x5, WtL + 0, 128, nullptr, nullptr, 0, q, nullptr, 128, 0,
            (long long)BLD);

        zero_mv_kernel<<<dim3(256), dim3(256), 0, stream>>>(mv);
        attn_kernel<<<dim3(2, 256), dim3(512), 0, stream>>>(q, kb, vf, paths, mv);

        gm_reduce_kernel<<<dim3(256), dim3(256), 0, stream>>>(mv, gm);
        topk_softmax_kernel<<<dim3(1), dim3(256), 0, stream>>>(gm, mv, delays, tc);

        // freq branch: tmpmix -> x5 (xf dead)
        mix_kernel<<<dim3(BLD / 2048), dim3(256), 0, stream>>>(x, tc, delays, x5);
        // a = tmpmix@W2' + spat@(0.1Wp') + x  -> kb
        wgemm_kernel<true, false><<<dim3(512, 1), dim3(256), 0, stream>>>(
            x5, WtL + 131072, 128, q, WtL + 49152, 128, kb, x, 128, 128, 0);
        // h = gelu(a @ F1) -> vf..x5 span (65536 x 256)
        wgemm_kernel<false, true><<<dim3(512, 2), dim3(256), 0, stream>>>(
            kb, WtL + 65536, 128, nullptr, nullptr, 0, vf, nullptr, 256, 0, 0);
        // x = h @ F2  (K=256: two B stages)
        wgemm_kernel<false, false><<<dim3(512, 1), dim3(256), 0, stream>>>(
            vf, WtL + 98304, 256, nullptr, nullptr, 0, x, nullptr, 128, 0, 0);
    }

    gather_out_kernel<<<dim3((Bn * Dn) / 256), dim3(256), 0, stream>>>(x, lengths, out);
}

// Round 11
// 445.381 us; speedup vs baseline: 1.1796x; 1.1796x over previous
//
#include <hip/hip_runtime.h>
#include <math.h>

// Problem constants
#define Bn 256
#define Ln 256
#define Dn 128
#define Hn 2
#define En 64
#define NLn 2
#define TOPKn 5
#define NUM_TOTALn 100000
#define BLD (Bn*Ln*Dn)      // 8388608 elements per activation buffer (bf16)
#define WT_LAYER 147456     // bf16 elements of weights per layer (incl W2T)

using frag_ab = __attribute__((ext_vector_type(8))) short;   // 8 bf16
using frag_cd = __attribute__((ext_vector_type(4))) float;   // 4 f32

__device__ inline short f2bf(float f) {
    union { float f; unsigned u; } c; c.f = f;
    unsigned r = (c.u + 0x7FFFu + ((c.u >> 16) & 1u)) >> 16;   // RNE
    return (short)r;
}
__device__ inline float bf2f(short s) {
    union { unsigned u; float f; } c; c.u = ((unsigned)(unsigned short)s) << 16;
    return c.f;
}

// ---------------------------------------------------------------------------
__global__ void beacon_kernel(float* out, float v) { out[0] = v; }

// Band-pass impulse response g_k[delta]; k=0: f in [51,128] (incl Nyquist),
// k=1: f in [0,77] (incl DC).
__global__ __launch_bounds__(256) void build_g_kernel(float* __restrict__ g) {
    int k = blockIdx.x;
    int d = threadIdx.x;
    int f1 = (k == 0) ? 51 : 1;
    int f2 = (k == 0) ? 127 : 77;
    double acc = (k == 0) ? 0.0 : 1.0;
    const double twopi_over_L = 6.283185307179586476925286766559 / 256.0;
    for (int f = f1; f <= f2; f++) acc += 2.0 * cos(twopi_over_L * (double)f * (double)d);
    if (k == 0) acc += (d & 1) ? -1.0 : 1.0;
    g[k * 256 + d] = (float)(acc / 256.0);
}

// Circulant matrices G_k[t][s] = g_k[(t-s)&255], stored bf16 (GEMM A operand)
__global__ __launch_bounds__(256) void build_G_kernel(const float* __restrict__ g,
                                                      short* __restrict__ G) {
    int k = blockIdx.x, t = blockIdx.y, s = threadIdx.x;
    G[((size_t)k * 256 + t) * 256 + s] = f2bf(g[k * 256 + ((t - s) & 255)]);
}

// x[b,t,d] = ego[paths[b,t], d] + pos[t, d]  -> bf16
__global__ __launch_bounds__(256) void build_x_kernel(const int* __restrict__ paths,
                                                      const float* __restrict__ ego,
                                                      const float* __restrict__ pos,
                                                      short* __restrict__ x) {
    int base = (blockIdx.x * 256 + threadIdx.x) * 4;
    int d = base & 127;
    int bl = base >> 7;
    int t = bl & 255;
    float4 e = *(const float4*)(ego + (size_t)paths[bl] * Dn + d);
    float4 p = *(const float4*)(pos + t * Dn + d);
    short4 s;
    s.x = f2bf(e.x + p.x); s.y = f2bf(e.y + p.y);
    s.z = f2bf(e.z + p.z); s.w = f2bf(e.w + p.w);
    *(short4*)&x[base] = s;
}

__global__ __launch_bounds__(256) void zero_mv_kernel(float* __restrict__ mv) {
    mv[blockIdx.x * 256 + threadIdx.x] = 0.0f;
}

// Weight cast+transpose+scale: in f32 [z][K][N] -> out bf16 [z][N][K] * scale
__global__ __launch_bounds__(256) void wtrans_kernel(const float* __restrict__ in,
                                                     short* __restrict__ out,
                                                     int K, int nmask, int nshift,
                                                     long long outLayerStride,
                                                     float scale) {
    int z = blockIdx.y;
    int idx = blockIdx.x * 256 + threadIdx.x;
    int n = idx & nmask;
    int k = idx >> nshift;
    out[(size_t)z * outLayerStride + (size_t)n * K + k] =
        f2bf(scale * in[(size_t)z * ((size_t)(nmask + 1) * K) + idx]);
}

// ---------------------------------------------------------------------------
// General MFMA bf16 GEMM (circulant filter + W2T precompute).
// A bf16 [M][K].  BT_FAST: B bf16 [N][K]; else B bf16 [K][N] transpose-staged.
// Operand-swapped MFMA -> coalesced short4 epilogue; register prefetch.
template<bool BT_FAST, bool GELU_EPI>
__global__ __launch_bounds__(256)
void mfma_gemm_kernel(const short* A, const short* Bp, short* C, const short* R,
                      int K, int lda, int ldb, int ldc, int ldr,
                      long long sA, long long sB, long long sC, long long sR,
                      long long sCsplit, float alpha, float beta) {
    int bz = blockIdx.z;
    A += (size_t)bz * sA; C += (size_t)bz * sC;
    if (R) R += (size_t)bz * sR;
    const short* Bt = Bp + (size_t)bz * sB;
    const int m0 = blockIdx.x * 128, n0 = blockIdx.y * 128;
    int n0c = n0;
    if (sCsplit) { C += (size_t)blockIdx.y * sCsplit; n0c = 0; }
    __shared__ short As[128 * 40];
    __shared__ short Bs[128 * 40];
    int tid = threadIdx.x;
    int lane = tid & 63, wave = tid >> 6;
    int wr = (wave >> 1) * 64, wc = (wave & 1) * 64;
    int l15 = lane & 15, qd = lane >> 4;

    frag_cd zero4 = {0.f, 0.f, 0.f, 0.f};
    frag_cd acc[4][4];
    #pragma unroll
    for (int i = 0; i < 4; i++)
        #pragma unroll
        for (int j = 0; j < 4; j++) acc[i][j] = zero4;

    int arow = tid >> 1, acg = (tid & 1) * 16;
    int bnrow = tid >> 1, bcg = (tid & 1) * 16;
    int bkk = tid & 31, bnb = (tid >> 5) * 16;

    int4 pa0, pa1, pb0, pb1;
    {
        const short* ap = A + (size_t)(m0 + arow) * lda + acg;
        pa0 = *(const int4*)ap; pa1 = *(const int4*)(ap + 8);
        if (BT_FAST) {
            const short* bp = Bt + (size_t)(n0 + bnrow) * ldb + bcg;
            pb0 = *(const int4*)bp; pb1 = *(const int4*)(bp + 8);
        } else {
            const short* bp = Bt + (size_t)bkk * ldb + n0 + bnb;
            pb0 = *(const int4*)bp; pb1 = *(const int4*)(bp + 8);
        }
    }

    for (int k0 = 0; k0 < K; k0 += 32) {
        __syncthreads();
        *(int4*)&As[arow * 40 + acg] = pa0;
        *(int4*)&As[arow * 40 + acg + 8] = pa1;
        if (BT_FAST) {
            *(int4*)&Bs[bnrow * 40 + bcg] = pb0;
            *(int4*)&Bs[bnrow * 40 + bcg + 8] = pb1;
        } else {
            short tmp[16];
            *(int4*)&tmp[0] = pb0; *(int4*)&tmp[8] = pb1;
            #pragma unroll
            for (int i = 0; i < 16; i++) Bs[(bnb + i) * 40 + bkk] = tmp[i];
        }
        __syncthreads();
        if (k0 + 32 < K) {
            const short* ap = A + (size_t)(m0 + arow) * lda + k0 + 32 + acg;
            pa0 = *(const int4*)ap; pa1 = *(const int4*)(ap + 8);
            if (BT_FAST) {
                const short* bp = Bt + (size_t)(n0 + bnrow) * ldb + k0 + 32 + bcg;
                pb0 = *(const int4*)bp; pb1 = *(const int4*)(bp + 8);
            } else {
                const short* bp = Bt + (size_t)(k0 + 32 + bkk) * ldb + n0 + bnb;
                pb0 = *(const int4*)bp; pb1 = *(const int4*)(bp + 8);
            }
        }
        frag_ab af[4], bf[4];
        #pragma unroll
        for (int ms = 0; ms < 4; ms++)
            af[ms] = *(frag_ab*)&As[(wr + ms * 16 + l15) * 40 + qd * 8];
        #pragma unroll
        for (int ns = 0; ns < 4; ns++)
            bf[ns] = *(frag_ab*)&Bs[(wc + ns * 16 + l15) * 40 + qd * 8];
        #pragma unroll
        for (int ms = 0; ms < 4; ms++)
            #pragma unroll
            for (int ns = 0; ns < 4; ns++)
                acc[ms][ns] = __builtin_amdgcn_mfma_f32_16x16x32_bf16(
                    bf[ns], af[ms], acc[ms][ns], 0, 0, 0);
    }
    #pragma unroll
    for (int ms = 0; ms < 4; ms++) {
        int m = m0 + wr + ms * 16 + l15;
        #pragma unroll
        for (int ns = 0; ns < 4; ns++) {
            int nb = wc + ns * 16 + qd * 4;
            float v[4];
            #pragma unroll
            for (int r = 0; r < 4; r++) v[r] = alpha * acc[ms][ns][r];
            if (R) {
                short4 r4 = *(const short4*)&R[(size_t)m * ldr + n0 + nb];
                v[0] += beta * bf2f(r4.x); v[1] += beta * bf2f(r4.y);
                v[2] += beta * bf2f(r4.z); v[3] += beta * bf2f(r4.w);
            }
            if (GELU_EPI) {
                #pragma unroll
                for (int r = 0; r < 4; r++)
                    v[r] = v[r] * 0.5f * (1.0f + erff(v[r] * 0.70710678118654752f));
            }
            short4 o;
            o.x = f2bf(v[0]); o.y = f2bf(v[1]); o.z = f2bf(v[2]); o.w = f2bf(v[3]);
            *(short4*)&C[(size_t)m * ldc + n0c + nb] = o;
        }
    }
}

static inline void mgemm(hipStream_t s, const short* A, const short* B, short* C,
                         const short* R, int M, int N, int K,
                         int lda, int ldb, int ldc, int ldr,
                         long long sA, long long sB, long long sC, long long sR,
                         int batch, float alpha, float beta, bool btFast, bool gelu,
                         long long sCsplit = 0) {
    dim3 grid(M / 128, N / 128, batch), block(256);
    if (btFast) {
        if (gelu) mfma_gemm_kernel<true, true ><<<grid, block, 0, s>>>(A, B, C, R, K, lda, ldb, ldc, ldr, sA, sB, sC, sR, sCsplit, alpha, beta);
        else      mfma_gemm_kernel<true, false><<<grid, block, 0, s>>>(A, B, C, R, K, lda, ldb, ldc, ldr, sA, sB, sC, sR, sCsplit, alpha, beta);
    } else {
        if (gelu) mfma_gemm_kernel<false, true ><<<grid, block, 0, s>>>(A, B, C, R, K, lda, ldb, ldc, ldr, sA, sB, sC, sR, sCsplit, alpha, beta);
        else      mfma_gemm_kernel<false, false><<<grid, block, 0, s>>>(A, B, C, R, K, lda, ldb, ldc, ldr, sA, sB, sC, sR, sCsplit, alpha, beta);
    }
}

// ---------------------------------------------------------------------------
// Big-tile weight GEMM: BM=256, BN=128, BK=32.  512 threads = 8 waves (4x2);
// LDS-staged A and B with register prefetch (round-9 proven structure, but
// half the barriers per output row and half the B re-fetch).
// C = A1@B1 [+ A2@B2] + R (+opt GELU).  A row stride == K (contiguous).
// B pre-transposed bf16 [N][K]; per-grid.y chunk: B += y*128*K.
// sCsplit != 0: C += y*sCsplit, C cols 0..127 (split outputs); else cols y*128.
template<bool DUAL, bool GELU_EPI>
__global__ __launch_bounds__(512)
void bgemm_kernel(const short* __restrict__ A1, const short* __restrict__ B1, int K1,
                  const short* __restrict__ A2, const short* __restrict__ B2, int K2,
                  short* C, const short* __restrict__ R, int ldc, int ldr,
                  long long sCsplit) {
    const int m0 = blockIdx.x * 256;
    int n0c;
    if (sCsplit) { C += (size_t)blockIdx.y * sCsplit; n0c = 0; }
    else         { n0c = blockIdx.y * 128; }
    __shared__ short As[256 * 40];   // [m][k] pad 40
    __shared__ short Bs[128 * 40];   // [n][k] pad 40
    int tid = threadIdx.x;
    int lane = tid & 63, wave = tid >> 6;
    int wr = (wave & 3) * 64, wc = (wave >> 2) * 64;
    int l15 = lane & 15, qd = lane >> 4;

    frag_cd zero4 = {0.f, 0.f, 0.f, 0.f};
    frag_cd acc[4][4];
    #pragma unroll
    for (int i = 0; i < 4; i++)
        #pragma unroll
        for (int j = 0; j < 4; j++) acc[i][j] = zero4;

    int arow = tid >> 1, acg = (tid & 1) * 16;   // A: 32B/thread
    int brow = tid >> 2, bcg = (tid & 3) * 8;    // B: 16B/thread

    #pragma unroll
    for (int pass = 0; pass < (DUAL ? 2 : 1); pass++) {
        const short* A = pass ? A2 : A1;
        const short* Bb = (pass ? B2 : B1);
        int K = pass ? K2 : K1;
        const short* Bt = Bb + (size_t)blockIdx.y * 128 * K;
        int4 pa0, pa1, pb0;
        {
            const short* ap = A + (size_t)(m0 + arow) * K + acg;
            pa0 = *(const int4*)ap; pa1 = *(const int4*)(ap + 8);
            pb0 = *(const int4*)(Bt + (size_t)brow * K + bcg);
        }
        for (int k0 = 0; k0 < K; k0 += 32) {
            __syncthreads();
            *(int4*)&As[arow * 40 + acg] = pa0;
            *(int4*)&As[arow * 40 + acg + 8] = pa1;
            *(int4*)&Bs[brow * 40 + bcg] = pb0;
            __syncthreads();
            if (k0 + 32 < K) {
                const short* ap = A + (size_t)(m0 + arow) * K + k0 + 32 + acg;
                pa0 = *(const int4*)ap; pa1 = *(const int4*)(ap + 8);
                pb0 = *(const int4*)(Bt + (size_t)brow * K + k0 + 32 + bcg);
            }
            frag_ab af[4], bf[4];
            #pragma unroll
            for (int ms = 0; ms < 4; ms++)
                af[ms] = *(frag_ab*)&As[(wr + ms * 16 + l15) * 40 + qd * 8];
            #pragma unroll
            for (int ns = 0; ns < 4; ns++)
                bf[ns] = *(frag_ab*)&Bs[(wc + ns * 16 + l15) * 40 + qd * 8];
            #pragma unroll
            for (int ms = 0; ms < 4; ms++)
                #pragma unroll
                for (int ns = 0; ns < 4; ns++)
                    acc[ms][ns] = __builtin_amdgcn_mfma_f32_16x16x32_bf16(
                        bf[ns], af[ms], acc[ms][ns], 0, 0, 0);
        }
    }
    #pragma unroll
    for (int ms = 0; ms < 4; ms++) {
        int m = m0 + wr + ms * 16 + l15;
        #pragma unroll
        for (int ns = 0; ns < 4; ns++) {
            int nb = wc + ns * 16 + qd * 4;
            float v[4];
            #pragma unroll
            for (int r = 0; r < 4; r++) v[r] = acc[ms][ns][r];
            if (R) {
                short4 r4 = *(const short4*)&R[(size_t)m * ldr + n0c + nb];
                v[0] += bf2f(r4.x); v[1] += bf2f(r4.y);
                v[2] += bf2f(r4.z); v[3] += bf2f(r4.w);
            }
            if (GELU_EPI) {
                #pragma unroll
                for (int r = 0; r < 4; r++)
                    v[r] = v[r] * 0.5f * (1.0f + erff(v[r] * 0.70710678118654752f));
            }
            short4 o;
            o.x = f2bf(v[0]); o.y = f2bf(v[1]); o.z = f2bf(v[2]); o.w = f2bf(v[3]);
            *(short4*)&C[(size_t)m * ldc + n0c + nb] = o;
        }
    }
}

// ---------------------------------------------------------------------------
// MFMA bf16 fused attention, one WG per (h, b).  512 threads = 8 waves.
// Fixed-max softmax (scores O(0.01)).  S stored DIAGONALLY (SD[tau][keyLocal],
// stride 66 -> conflict-free mv reduction).  Denominator via ones-column in vT.
__global__ __launch_bounds__(512, 4) void attn_kernel(short* q,
        const short* __restrict__ kb, const short* __restrict__ vf,
        const int* __restrict__ paths, float* __restrict__ mv) {
    int h = blockIdx.x, b = blockIdx.y;
    __shared__ short SB[256 * 72];   // phase0: q staging (stride 72); loop: SD (stride 66)
    __shared__ short ks[64 * 72];
    __shared__ short vT[80 * 72];
    __shared__ float masks[256];
    __shared__ float mvpart[512];
    int tid = threadIdx.x;
    int lane = tid & 63, wave = tid >> 6;
    int l15 = lane & 15, qd = lane >> 4;
    if (tid < 256) masks[tid] = (paths[b * 256 + tid] < NUM_TOTALn) ? 0.0f : -10000.0f;
    {
        int e0 = tid * 2;
        #pragma unroll
        for (int i = 0; i < 2; i++) {
            int e = e0 + i;
            int row = 64 + (e >> 6), col = e & 63;
            vT[row * 72 + col] = (row == 64) ? (short)0x3F80 : (short)0;
        }
    }
    short* qg = q + ((size_t)b << 15) + (size_t)h * 64;
    const short* kg = kb + ((size_t)b << 15) + (size_t)h * 64;
    const short* vg = vf + ((size_t)b << 15) + (size_t)h * 64;

    #pragma unroll
    for (int p = 0; p < 4; p++) {
        int chunk = p * 512 + tid;
        int r = chunk >> 3, cb = (chunk & 7) * 8;
        *(frag_ab*)&SB[r * 72 + cb] = *(const frag_ab*)(qg + (size_t)r * 128 + cb);
    }
    __syncthreads();
    int myrow = wave * 32;
    frag_ab aq[2][2];
    #pragma unroll
    for (int mt = 0; mt < 2; mt++)
        #pragma unroll
        for (int hf = 0; hf < 2; hf++)
            aq[mt][hf] = *(frag_ab*)&SB[(myrow + mt * 16 + l15) * 72 + hf * 32 + qd * 8];

    frag_cd zero4 = {0.f, 0.f, 0.f, 0.f};
    frag_cd oacc[2][5];
    #pragma unroll
    for (int mt = 0; mt < 2; mt++)
        #pragma unroll
        for (int et = 0; et < 5; et++) oacc[mt][et] = zero4;
    float macc = 0.0f;
    int tau = tid & 255, half = tid >> 8;

    for (int jt = 0; jt < 4; jt++) {
        __syncthreads();
        {
            int r = tid >> 3, cb = (tid & 7) * 8;
            *(frag_ab*)&ks[r * 72 + cb] =
                *(const frag_ab*)(kg + (size_t)(jt * 64 + r) * 128 + cb);
            frag_ab v8 = *(const frag_ab*)(vg + (size_t)(jt * 64 + r) * 128 + cb);
            #pragma unroll
            for (int i = 0; i < 8; i++) vT[(cb + i) * 72 + r] = v8[i];
        }
        __syncthreads();
        #pragma unroll
        for (int mt = 0; mt < 2; mt++) {
            #pragma unroll
            for (int nt = 0; nt < 4; nt++) {
                frag_ab b0 = *(frag_ab*)&ks[(nt * 16 + l15) * 72 + qd * 8];
                frag_ab b1 = *(frag_ab*)&ks[(nt * 16 + l15) * 72 + 32 + qd * 8];
                frag_cd c = zero4;
                c = __builtin_amdgcn_mfma_f32_16x16x32_bf16(aq[mt][0], b0, c, 0, 0, 0);
                c = __builtin_amdgcn_mfma_f32_16x16x32_bf16(aq[mt][1], b1, c, 0, 0, 0);
                int keyLocal = nt * 16 + l15;
                #pragma unroll
                for (int r = 0; r < 4; r++) {
                    int row = myrow + mt * 16 + qd * 4 + r;
                    int tt = (row - jt * 64 - keyLocal) & 255;
                    SB[tt * 66 + keyLocal] = f2bf(c[r] * 0.125f);
                }
            }
        }
        __syncthreads();
        {
            const int* SD32 = (const int*)&SB[tau * 66 + half * 32];
            #pragma unroll
            for (int i = 0; i < 16; i++) {
                int pk = SD32[i];
                macc += bf2f((short)(pk & 0xFFFF)) + bf2f((short)(pk >> 16));
            }
        }
        #pragma unroll
        for (int mt = 0; mt < 2; mt++) {
            int row = myrow + mt * 16 + l15;
            #pragma unroll
            for (int hf = 0; hf < 2; hf++) {
                int kl0 = hf * 32 + qd * 8;
                frag_ab pfrag;
                #pragma unroll
                for (int j = 0; j < 8; j++) {
                    int kl = kl0 + j;
                    int tt = (row - jt * 64 - kl) & 255;
                    float s = bf2f(SB[tt * 66 + kl]);
                    pfrag[j] = f2bf(__expf(s + masks[jt * 64 + kl]));
                }
                #pragma unroll
                for (int et = 0; et < 5; et++) {
                    frag_ab bv = *(frag_ab*)&vT[(et * 16 + l15) * 72 + hf * 32 + qd * 8];
                    oacc[mt][et] = __builtin_amdgcn_mfma_f32_16x16x32_bf16(pfrag, bv, oacc[mt][et], 0, 0, 0);
                }
            }
        }
    }
    __syncthreads();
    mvpart[tid] = macc;
    __syncthreads();
    if (tid < 256)
        atomicAdd(&mv[b * 256 + tid], (mvpart[tid] + mvpart[tid + 256]) * 0.0625f);
    #pragma unroll
    for (int mt = 0; mt < 2; mt++) {
        #pragma unroll
        for (int r = 0; r < 4; r++) {
            float l = oacc[mt][4][r];
            l = __shfl(l, (lane & 48));
            float inv = 1.0f / l;
            int row = myrow + mt * 16 + qd * 4 + r;
            #pragma unroll
            for (int et = 0; et < 4; et++)
                qg[(size_t)row * 128 + et * 16 + l15] = f2bf(oacc[mt][et][r] * inv);
        }
    }
}

// ---------------------------------------------------------------------------
__global__ __launch_bounds__(256) void gm_reduce_kernel(const float* __restrict__ mv,
                                                        float* __restrict__ gm) {
    int tau = blockIdx.x;
    int b = threadIdx.x;
    __shared__ float red[256];
    red[b] = mv[b * 256 + tau];
    __syncthreads();
    for (int s = 128; s > 0; s >>= 1) { if (b < s) red[b] += red[b + s]; __syncthreads(); }
    if (b == 0) gm[tau] = red[0] * (1.0f / 256.0f);
}

__global__ __launch_bounds__(256) void topk_softmax_kernel(const float* __restrict__ gm,
                                                           const float* __restrict__ mv,
                                                           int* __restrict__ delays,
                                                           float* __restrict__ tc) {
    __shared__ float vsh[256];
    __shared__ int ish[256];
    __shared__ int dsh[TOPKn];
    int tid = threadIdx.x;
    float v = gm[tid];
    for (int t = 0; t < TOPKn; t++) {
        vsh[tid] = v; ish[tid] = tid;
        __syncthreads();
        for (int s = 128; s > 0; s >>= 1) {
            if (tid < s) {
                float v2 = vsh[tid + s]; int i2 = ish[tid + s];
                if (v2 > vsh[tid] || (v2 == vsh[tid] && i2 < ish[tid])) {
                    vsh[tid] = v2; ish[tid] = i2;
                }
            }
            __syncthreads();
        }
        if (tid == 0) { dsh[t] = ish[0]; delays[t] = ish[0]; }
        __syncthreads();
        if (tid == dsh[t]) v = -1e30f;
        __syncthreads();
    }
    int b = tid;
    float w[TOPKn];
    float m = -1e30f;
    #pragma unroll
    for (int j = 0; j < TOPKn; j++) { w[j] = mv[b * 256 + dsh[j]]; m = fmaxf(m, w[j]); }
    float ssum = 0.0f;
    #pragma unroll
    for (int j = 0; j < TOPKn; j++) { w[j] = expf(w[j] - m); ssum += w[j]; }
    #pragma unroll
    for (int j = 0; j < TOPKn; j++) tc[b * TOPKn + j] = w[j] / ssum;
}

__global__ __launch_bounds__(256) void mix_kernel(const short* __restrict__ x,
                                                  const float* __restrict__ tc,
                                                  const int* __restrict__ delays,
                                                  short* __restrict__ out) {
    int idx = (blockIdx.x * 256 + threadIdx.x) * 8;
    int d = idx & 127;
    int t = (idx >> 7) & 255;
    int b = idx >> 15;
    const short* xb = x + ((size_t)b << 15);
    float acc[8] = {0, 0, 0, 0, 0, 0, 0, 0};
    #pragma unroll
    for (int j = 0; j < TOPKn; j++) {
        float w = tc[b * TOPKn + j];
        frag_ab v8 = *(const frag_ab*)(xb + (((t + delays[j]) & 255) << 7) + d);
        #pragma unroll
        for (int i = 0; i < 8; i++) acc[i] += w * bf2f(v8[i]);
    }
    frag_ab o;
    #pragma unroll
    for (int i = 0; i < 8; i++) o[i] = f2bf(acc[i]);
    *(frag_ab*)(out + idx) = o;
}

__global__ __launch_bounds__(256) void gather_out_kernel(const short* __restrict__ x,
                                                         const int* __restrict__ lengths,
                                                         float* __restrict__ out) {
    int idx = blockIdx.x * 256 + threadIdx.x;
    int d = idx & 127;
    int b = idx >> 7;
    out[idx] = bf2f(x[((size_t)b << 15) + (size_t)(lengths[b] - 1) * Dn + d]);
}

// ---------------------------------------------------------------------------
extern "C" void kernel_launch(void* const* d_in, const int* in_sizes, int n_in,
                              void* d_out, int out_size, void* d_ws, size_t ws_size,
                              hipStream_t stream) {
    const int* paths    = (const int*)d_in[0];
    const int* lengths  = (const int*)d_in[1];
    const float* ego    = (const float*)d_in[4];
    const float* pos    = (const float*)d_in[5];
    const float* Wq     = (const float*)d_in[6];
    const float* Wk     = (const float*)d_in[7];
    const float* Wv     = (const float*)d_in[8];
    const float* Wp     = (const float*)d_in[9];
    const float* F1     = (const float*)d_in[10];
    const float* F2     = (const float*)d_in[11];
    float* out = (float*)d_out;

    const size_t need = (size_t)5 * BLD * 2 + 512 * 4 + 131072 * 2 + 65536 * 4
                        + 256 * 4 + 1280 * 4 + 16 * 4 + (size_t)NLn * WT_LAYER * 2;
    if (ws_size < need) {
        beacon_kernel<<<dim3(1), dim3(1), 0, stream>>>(out, (float)(ws_size >> 20));
        return;
    }

    short* x    = (short*)d_ws;
    short* q    = x + (size_t)1 * BLD;   // q~ -> spat
    short* kb   = x + (size_t)2 * BLD;   // k~ -> a
    short* vf   = x + (size_t)3 * BLD;   // v~ -> h (spans vf+x5)
    short* x5   = x + (size_t)4 * BLD;   // xf -> tmpmix -> h(hi)
    float* g    = (float*)(x + (size_t)5 * BLD);
    short* Gb   = (short*)(g + 512);
    float* mv   = (float*)(Gb + 131072);
    float* gm   = mv + 65536;
    float* tc   = gm + 256;
    int* delays = (int*)(tc + 1280);
    short* Wt   = (short*)(delays + 16);

    build_g_kernel<<<dim3(2), dim3(256), 0, stream>>>(g);
    build_G_kernel<<<dim3(2, 256), dim3(256), 0, stream>>>(g, Gb);
    build_x_kernel<<<dim3(BLD / 1024), dim3(256), 0, stream>>>(paths, ego, pos, x);

    // Wt per layer: [0]=Wq^T | [16384]=Wk^T | [32768]=Wv^T | [49152]=0.1*Wp^T
    //               [65536]=F1^T | [98304]=F2^T | [131072]=W2^T=0.9*(Wv@Wp)^T
    wtrans_kernel<<<dim3(64, NLn),  dim3(256), 0, stream>>>(Wq, Wt + 0,     128, 127, 7, WT_LAYER, 1.0f);
    wtrans_kernel<<<dim3(64, NLn),  dim3(256), 0, stream>>>(Wk, Wt + 16384, 128, 127, 7, WT_LAYER, 1.0f);
    wtrans_kernel<<<dim3(64, NLn),  dim3(256), 0, stream>>>(Wv, Wt + 32768, 128, 127, 7, WT_LAYER, 1.0f);
    wtrans_kernel<<<dim3(64, NLn),  dim3(256), 0, stream>>>(Wp, Wt + 49152, 128, 127, 7, WT_LAYER, 0.1f);
    wtrans_kernel<<<dim3(128, NLn), dim3(256), 0, stream>>>(F1, Wt + 65536, 128, 255, 8, WT_LAYER, 1.0f);
    wtrans_kernel<<<dim3(128, NLn), dim3(256), 0, stream>>>(F2, Wt + 98304, 256, 127, 7, WT_LAYER, 1.0f);
    for (int k = 0; k < NLn; k++) {
        short* WtL = Wt + (size_t)k * WT_LAYER;
        mgemm(stream, WtL + 49152, WtL + 32768, WtL + 131072, nullptr,
              128, 128, 128, 128, 128, 128, 0, 0, 0, 0, 0, 1,
              9.0f, 0.0f, false, false);
    }

    for (int k = 0; k < NLn; k++) {
        const short* WtL = Wt + (size_t)k * WT_LAYER;
        // xf = G_k @ x[b] (band filter; slow-path B) -> x5
        mgemm(stream, Gb + (size_t)k * 65536, x, x5, nullptr,
              256, 128, 256, 256, 128, 128, 0,
              0, 32768, 32768, 0, 256, 1.0f, 0.0f, false, false);
        // fused projections: A=x5, B=[Wq^T;Wk^T;Wv^T], N=384 split-C (BM=256)
        bgemm_kernel<false, false><<<dim3(256, 3), dim3(512), 0, stream>>>(
            x5, WtL + 0, 128, nullptr, nullptr, 0, q, nullptr, 128, 0,
            (long long)BLD);

        zero_mv_kernel<<<dim3(256), dim3(256), 0, stream>>>(mv);
        attn_kernel<<<dim3(2, 256), dim3(512), 0, stream>>>(q, kb, vf, paths, mv);

        gm_reduce_kernel<<<dim3(256), dim3(256), 0, stream>>>(mv, gm);
        topk_softmax_kernel<<<dim3(1), dim3(256), 0, stream>>>(gm, mv, delays, tc);

        // freq branch: tmpmix -> x5 (xf dead)
        mix_kernel<<<dim3(BLD / 2048), dim3(256), 0, stream>>>(x, tc, delays, x5);
        // a = tmpmix@W2' + spat@(0.1Wp') + x  -> kb
        bgemm_kernel<true, false><<<dim3(256, 1), dim3(512), 0, stream>>>(
            x5, WtL + 131072, 128, q, WtL + 49152, 128, kb, x, 128, 128, 0);
        // h = gelu(a @ F1) -> vf..x5 span (65536 x 256)
        bgemm_kernel<false, true><<<dim3(256, 2), dim3(512), 0, stream>>>(
            kb, WtL + 65536, 128, nullptr, nullptr, 0, vf, nullptr, 256, 0, 0);
        // x = h @ F2  (K=256)
        bgemm_kernel<false, false><<<dim3(256, 1), dim3(512), 0, stream>>>(
            vf, WtL + 98304, 256, nullptr, nullptr, 0, x, nullptr, 128, 0, 0);
    }

    gather_out_kernel<<<dim3((Bn * Dn) / 256), dim3(256), 0, stream>>>(x, lengths, out);
}